// Round 5
// baseline (249.382 us; speedup 1.0000x reference)
//
#include <hip/hip_runtime.h>

constexpr int kB  = 16;
constexpr int kM  = 512;
constexpr int kS  = 32;
constexpr int kE  = 128;
constexpr int kV  = 32000;
constexpr int kVN = kV - 1;   // nil (zero) row index
constexpr int kMS = 132;      // padded LDS row stride (floats)

// -------------------------------------------------------------------------
// Fence-free spin barrier over the 32 blocks of one b-group (co-resident via
// cooperative launch). Cross-block data uses agent-scope RELAXED atomics
// (coherent accesses, no L2 writeback/invalidate storms — R3 lesson).
// -------------------------------------------------------------------------
__device__ __forceinline__ void group_barrier(unsigned* ctr, unsigned target)
{
    __syncthreads();                       // drains each thread's vmcnt
    if (threadIdx.x == 0) {
        __hip_atomic_fetch_add(ctr, 1u, __ATOMIC_RELEASE, __HIP_MEMORY_SCOPE_AGENT);
        while (__hip_atomic_load(ctr, __ATOMIC_RELAXED, __HIP_MEMORY_SCOPE_AGENT) < target)
            __builtin_amdgcn_s_sleep(2);
    }
    __syncthreads();
}
__device__ __forceinline__ void cstore(float* p, float v) {
    __hip_atomic_store(p, v, __ATOMIC_RELAXED, __HIP_MEMORY_SCOPE_AGENT);
}
__device__ __forceinline__ float cload(const float* p) {
    return __hip_atomic_load(p, __ATOMIC_RELAXED, __HIP_MEMORY_SCOPE_AGENT);
}

// -------------------------------------------------------------------------
// Fused kernel (cooperative, 512 blocks x 256 threads).
// Block (b = bid&15, j = bid>>4): owns story rows [j*16, j*16+16) of batch b.
//  Phase E: gather-embed own 16 rows of memory & output DIRECTLY into LDS
//           (no global round-trip). enc[s][e] = 1+(e-63)(s-15)/1024 exact.
//  Phase Q: redundant per-block query embedding (16 KB gather).
//  Hops (x3, ONE barrier each): local scores+exp -> publish numer/denom
//           partials -> barrier -> redundant combine + W matmul.
// j==0 publishes relu(q) to xg (transposed [E,B]).
// -------------------------------------------------------------------------
__global__ __launch_bounds__(256) void fused_kernel(
    const int*   __restrict__ queries,   // [B,S]
    const int*   __restrict__ stories,   // [B*M,S]
    const float* __restrict__ q_bias,    // [VN,E]
    const float* __restrict__ st_bias,   // [VN,E]
    const float* __restrict__ out_bias,  // [VN,E]
    const float* __restrict__ mem_bias,  // [M,E]
    const float* __restrict__ w_int,     // [E,E]
    const float* __restrict__ w_out,     // [E,E]
    float*       __restrict__ numer,     // [2,B,32,E]
    float*       __restrict__ denom,     // [2,B,32]
    float*       __restrict__ xg,        // [E,B]
    unsigned*    __restrict__ bar)       // [B] counters (pre-zeroed)
{
    __shared__ __align__(16) float mem_lds[16 * kMS];
    __shared__ __align__(16) float out_lds[16 * kMS];
    __shared__ float sc_q[16];
    __shared__ __align__(16) float q_s[kE];
    __shared__ float xb[kE];
    __shared__ __align__(16) float part8[8][kE];
    __shared__ float dtot;
    __shared__ int sidx[16 * kS];
    __shared__ int qidx[kS];

    const int bid = blockIdx.x;
    const int b   = bid & 15;            // all 32 blocks of b on one XCD
    const int j   = bid >> 4;            // 0..31
    const int t   = threadIdx.x;
    unsigned* ctr = bar + b;

    const int row0 = b * kM + j * 16;    // first global story row
    sidx[t]       = stories[row0 * kS + t];
    sidx[t + 256] = stories[row0 * kS + 256 + t];
    if (t < kS) qidx[t] = queries[b * kS + t];
    __syncthreads();

    // ---- Phase E: embed 16 rows into LDS. group g (32 lanes) -> rows 2g,2g+1
    {
        const int g = t >> 5, l = t & 31, e0 = l * 4;
        const int r0 = 2 * g, r1 = 2 * g + 1;
        const float f0 = (float)(e0 - 63) * (1.0f / 1024.0f);
        const float f1 = (float)(e0 - 62) * (1.0f / 1024.0f);
        const float f2 = (float)(e0 - 61) * (1.0f / 1024.0f);
        const float f3 = (float)(e0 - 60) * (1.0f / 1024.0f);
        float4 am0 = {0,0,0,0}, ao0 = {0,0,0,0};
        float4 am1 = {0,0,0,0}, ao1 = {0,0,0,0};
        #pragma unroll 4
        for (int s = 0; s < kS; ++s) {
            const float sf = (float)(s - 15);
            const float c0 = fmaf(f0, sf, 1.f), c1 = fmaf(f1, sf, 1.f);
            const float c2 = fmaf(f2, sf, 1.f), c3 = fmaf(f3, sf, 1.f);
            const int i0 = sidx[r0 * kS + s];
            const int i1 = sidx[r1 * kS + s];
            if (i0 < kVN) {
                const float4 vm = *(const float4*)&st_bias [(size_t)i0 * kE + e0];
                const float4 vo = *(const float4*)&out_bias[(size_t)i0 * kE + e0];
                am0.x = fmaf(vm.x, c0, am0.x); am0.y = fmaf(vm.y, c1, am0.y);
                am0.z = fmaf(vm.z, c2, am0.z); am0.w = fmaf(vm.w, c3, am0.w);
                ao0.x = fmaf(vo.x, c0, ao0.x); ao0.y = fmaf(vo.y, c1, ao0.y);
                ao0.z = fmaf(vo.z, c2, ao0.z); ao0.w = fmaf(vo.w, c3, ao0.w);
            }
            if (i1 < kVN) {
                const float4 vm = *(const float4*)&st_bias [(size_t)i1 * kE + e0];
                const float4 vo = *(const float4*)&out_bias[(size_t)i1 * kE + e0];
                am1.x = fmaf(vm.x, c0, am1.x); am1.y = fmaf(vm.y, c1, am1.y);
                am1.z = fmaf(vm.z, c2, am1.z); am1.w = fmaf(vm.w, c3, am1.w);
                ao1.x = fmaf(vo.x, c0, ao1.x); ao1.y = fmaf(vo.y, c1, ao1.y);
                ao1.z = fmaf(vo.z, c2, ao1.z); ao1.w = fmaf(vo.w, c3, ao1.w);
            }
        }
        const int m0 = j * 16 + r0, m1 = j * 16 + r1;   // (row % 512)
        const float4 mb0 = *(const float4*)&mem_bias[m0 * kE + e0];
        const float4 mb1 = *(const float4*)&mem_bias[m1 * kE + e0];
        am0.x += mb0.x; am0.y += mb0.y; am0.z += mb0.z; am0.w += mb0.w;
        am1.x += mb1.x; am1.y += mb1.y; am1.z += mb1.z; am1.w += mb1.w;
        *(float4*)&mem_lds[r0 * kMS + e0] = am0;
        *(float4*)&mem_lds[r1 * kMS + e0] = am1;
        *(float4*)&out_lds[r0 * kMS + e0] = ao0;
        *(float4*)&out_lds[r1 * kMS + e0] = ao1;
    }

    // ---- Phase Q: query embedding (redundant per block) ----
    {
        const int g = t >> 5, l = t & 31, e0 = l * 4;
        const float f0 = (float)(e0 - 63) * (1.0f / 1024.0f);
        const float f1 = (float)(e0 - 62) * (1.0f / 1024.0f);
        const float f2 = (float)(e0 - 61) * (1.0f / 1024.0f);
        const float f3 = (float)(e0 - 60) * (1.0f / 1024.0f);
        float4 a = {0,0,0,0};
        #pragma unroll
        for (int sj = 0; sj < 4; ++sj) {
            const int s   = g * 4 + sj;
            const int idx = qidx[s];
            const float sf = (float)(s - 15);
            if (idx < kVN) {
                const float4 v = *(const float4*)&q_bias[(size_t)idx * kE + e0];
                a.x = fmaf(v.x, fmaf(f0, sf, 1.f), a.x);
                a.y = fmaf(v.y, fmaf(f1, sf, 1.f), a.y);
                a.z = fmaf(v.z, fmaf(f2, sf, 1.f), a.z);
                a.w = fmaf(v.w, fmaf(f3, sf, 1.f), a.w);
            }
        }
        *(float4*)&part8[g][e0] = a;
    }
    __syncthreads();
    if (t < kE) {
        float s = 0.f;
        #pragma unroll
        for (int g = 0; g < 8; ++g) s += part8[g][t];
        q_s[t] = s;
    }
    __syncthreads();

    for (int hop = 0; hop < 3; ++hop) {
        const int pb = hop & 1;
        // ---- scores: 16 lanes per row, each lane 8 e's; exp (no max-sub,
        //      |score| = O(1) for this weight scale — validated R4) ----
        {
            const int rw = t >> 4, l16 = t & 15;
            const float4* qv = (const float4*)&q_s[l16 * 8];
            const float4* mv = (const float4*)&mem_lds[rw * kMS + l16 * 8];
            const float4 m0 = mv[0], m1 = mv[1], qa = qv[0], qb = qv[1];
            float d = 0.f;
            d = fmaf(m0.x, qa.x, d); d = fmaf(m0.y, qa.y, d);
            d = fmaf(m0.z, qa.z, d); d = fmaf(m0.w, qa.w, d);
            d = fmaf(m1.x, qb.x, d); d = fmaf(m1.y, qb.y, d);
            d = fmaf(m1.z, qb.z, d); d = fmaf(m1.w, qb.w, d);
            d += __shfl_down(d, 8);
            d += __shfl_down(d, 4);
            d += __shfl_down(d, 2);
            d += __shfl_down(d, 1);
            if (l16 == 0) sc_q[rw] = __expf(d);
        }
        __syncthreads();

        // ---- publish partials: numer[e] (t<128), denom (t==255) ----
        if (t < kE) {
            float acc = 0.f;
            #pragma unroll
            for (int m = 0; m < 16; ++m)
                acc = fmaf(sc_q[m], out_lds[m * kMS + t], acc);
            cstore(&numer[(((size_t)pb * kB + b) * 32 + j) * kE + t], acc);
        } else if (t == 255) {
            float d = 0.f;
            #pragma unroll
            for (int m = 0; m < 16; ++m) d += sc_q[m];
            cstore(&denom[((size_t)pb * kB + b) * 32 + j], d);
        }

        group_barrier(ctr, 32u * (hop + 1));

        // ---- combine: denom total (one wave), then xb = q + numer/den ----
        if (t < 64) {
            float d = (t < 32) ? cload(&denom[((size_t)pb * kB + b) * 32 + t]) : 0.f;
            #pragma unroll
            for (int off = 32; off; off >>= 1) d += __shfl_down(d, off);
            if (t == 0) dtot = d;
        }
        __syncthreads();
        if (t < kE) {
            const float* nn = numer + ((size_t)pb * kB + b) * 32 * kE;
            float ns = 0.f;
            #pragma unroll
            for (int jj = 0; jj < 32; ++jj) ns += cload(&nn[jj * kE + t]);
            xb[t] = q_s[t] + ns / dtot;
        }
        __syncthreads();

        // ---- q' = xb @ W (redundant; 2 k-halves of 64) ----
        {
            const float* w = (hop == 2) ? w_out : w_int;
            const int e = t & 127, h = t >> 7;
            float acc = 0.f;
            #pragma unroll 8
            for (int k = 0; k < 64; ++k) {
                const int kk = h * 64 + k;
                acc = fmaf(xb[kk], w[kk * kE + e], acc);
            }
            part8[h][e] = acc;
        }
        __syncthreads();
        if (t < kE) q_s[t] = part8[0][t] + part8[1][t];
        __syncthreads();
    }

    if (j == 0 && t < kE) xg[t * kB + b] = fmaxf(q_s[t], 0.f);
}

// -------------------------------------------------------------------------
// Final: out[b,v] = sum_e relu_x[b,e] * w_final[e,v]. 250 blocks x 256:
// v = bid*128 + (t&127); e-half = t>>7; xg transposed -> uniform loads.
// -------------------------------------------------------------------------
__global__ __launch_bounds__(256) void final_kernel(
    const float* __restrict__ xg,   // [E,B]
    const float* __restrict__ wf,   // [E,V]
    float*       __restrict__ out)  // [B,V]
{
    __shared__ float ps[128 * kB];
    const int t = threadIdx.x;
    const int v = blockIdx.x * 128 + (t & 127);
    const int h = t >> 7;

    float acc[kB];
    #pragma unroll
    for (int b = 0; b < kB; ++b) acc[b] = 0.f;

    const int e0 = h * 64;
    #pragma unroll 4
    for (int ei = 0; ei < 64; ++ei) {
        const int e = e0 + ei;
        const float wv = wf[(size_t)e * kV + v];
        const float* xr = xg + e * kB;
        #pragma unroll
        for (int b = 0; b < kB; ++b) acc[b] = fmaf(xr[b], wv, acc[b]);
    }
    if (h == 1) {
        #pragma unroll
        for (int b = 0; b < kB; ++b) ps[(t & 127) * kB + b] = acc[b];
    }
    __syncthreads();
    if (h == 0) {
        #pragma unroll
        for (int b = 0; b < kB; ++b)
            out[(size_t)b * kV + v] = acc[b] + ps[(t & 127) * kB + b];
    }
}

// -------------------------------------------------------------------------
extern "C" void kernel_launch(void* const* d_in, const int* in_sizes, int n_in,
                              void* d_out, int out_size, void* d_ws, size_t ws_size,
                              hipStream_t stream)
{
    const int*   queries  = (const int*)  d_in[0];
    const int*   stories  = (const int*)  d_in[1];
    const float* q_bias   = (const float*)d_in[2];
    const float* st_bias  = (const float*)d_in[3];
    const float* mem_bias = (const float*)d_in[4];
    const float* out_bias = (const float*)d_in[5];
    const float* w_int    = (const float*)d_in[6];
    const float* w_out    = (const float*)d_in[7];
    const float* w_final  = (const float*)d_in[8];
    float* out = (float*)d_out;

    // ws (floats): numer[2*16*32*128] | denom[2*16*32] | xg[128*16] | bar[16]
    float* numer  = (float*)d_ws;
    float* denom  = numer + 2 * kB * 32 * kE;    // 131072
    float* xg     = denom + 2 * kB * 32;         // 1024
    unsigned* bar = (unsigned*)(xg + kE * kB);   // 2048

    hipMemsetAsync(bar, 0, kB * sizeof(unsigned), stream);

    void* args[] = {
        (void*)&queries, (void*)&stories, (void*)&q_bias, (void*)&st_bias,
        (void*)&out_bias, (void*)&mem_bias, (void*)&w_int, (void*)&w_out,
        (void*)&numer, (void*)&denom, (void*)&xg, (void*)&bar
    };
    hipLaunchCooperativeKernel((const void*)fused_kernel,
                               dim3(512), dim3(256), args, 0, stream);

    final_kernel<<<dim3(kV / 128), dim3(256), 0, stream>>>(xg, w_final, out);
}

// Round 6
// 166.391 us; speedup vs baseline: 1.4988x; 1.4988x over previous
//
#include <hip/hip_runtime.h>

constexpr int kB  = 16;
constexpr int kM  = 512;
constexpr int kS  = 32;
constexpr int kE  = 128;
constexpr int kV  = 32000;
constexpr int kVN = kV - 1;   // nil (zero) row index
constexpr int kMS = 132;      // padded LDS stride for mem tile

// -------------------------------------------------------------------------
// Kernel 1: story embeddings. 2 rows per 256-thread block, grid = 4096.
// 8 groups of 32 lanes; group = (row-in-pair, s-phase); each lane gathers
// float4 for 8 s values x 2 tables -> 16 UNCONDITIONAL loads in flight
// (nil row handled by clamp + zero weight, not a branch).
// enc[s][e] = 1 + (e-63)(s-15)/1024 (exact f32 match of numpy formula).
// Block 0 also zeroes the hops barrier counters (saves a memset dispatch).
// -------------------------------------------------------------------------
__global__ __launch_bounds__(256) void embed_stories_kernel(
    const int*   __restrict__ stories,   // [B,M,S]
    const float* __restrict__ st_bias,   // [VN,E]
    const float* __restrict__ out_bias,  // [VN,E]
    const float* __restrict__ mem_bias,  // [M,E]
    float*       __restrict__ memory,    // [B,M,E]
    float*       __restrict__ output,    // [B,M,E]
    unsigned*    __restrict__ bar)       // [B] counters -> zeroed by block 0
{
    __shared__ int sidx[2][kS];
    __shared__ __align__(16) float pm[8][kE];
    __shared__ __align__(16) float po[8][kE];

    const int t    = threadIdx.x;
    const int row0 = blockIdx.x * 2;
    if (t < 64) sidx[t >> 5][t & 31] = stories[row0 * kS + t];
    if (blockIdx.x == 0 && t < kB) bar[t] = 0u;
    __syncthreads();

    const int g    = t >> 5;
    const int lane = t & 31;
    const int p    = g >> 2;       // row of pair
    const int ph   = g & 3;        // s-phase
    const int e0   = lane * 4;
    const float ef0 = (float)(e0 - 63), ef1 = (float)(e0 - 62);
    const float ef2 = (float)(e0 - 61), ef3 = (float)(e0 - 60);

    float4 am = {0.f, 0.f, 0.f, 0.f};
    float4 ao = {0.f, 0.f, 0.f, 0.f};
    #pragma unroll
    for (int j = 0; j < 8; ++j) {
        const int s   = ph * 8 + j;
        const int idx = sidx[p][s];
        const int ci  = idx < kVN ? idx : (kVN - 1);       // clamped row
        const float live = (idx < kVN) ? 1.0f : 0.0f;      // nil -> weight 0
        const float sf = (float)(s - 15) * (1.0f / 1024.0f);
        const float4 vm = *(const float4*)(st_bias  + (size_t)ci * kE + e0);
        const float4 vo = *(const float4*)(out_bias + (size_t)ci * kE + e0);
        const float c0 = fmaf(ef0, sf, 1.0f) * live;
        const float c1 = fmaf(ef1, sf, 1.0f) * live;
        const float c2 = fmaf(ef2, sf, 1.0f) * live;
        const float c3 = fmaf(ef3, sf, 1.0f) * live;
        am.x = fmaf(vm.x, c0, am.x); am.y = fmaf(vm.y, c1, am.y);
        am.z = fmaf(vm.z, c2, am.z); am.w = fmaf(vm.w, c3, am.w);
        ao.x = fmaf(vo.x, c0, ao.x); ao.y = fmaf(vo.y, c1, ao.y);
        ao.z = fmaf(vo.z, c2, ao.z); ao.w = fmaf(vo.w, c3, ao.w);
    }
    *(float4*)&pm[g][e0] = am;
    *(float4*)&po[g][e0] = ao;
    __syncthreads();

    const int pr = t >> 7;
    const int e  = t & 127;
    const int row = row0 + pr;
    const int m   = row & (kM - 1);
    const float sm = pm[pr * 4 + 0][e] + pm[pr * 4 + 1][e] +
                     pm[pr * 4 + 2][e] + pm[pr * 4 + 3][e];
    const float so = po[pr * 4 + 0][e] + po[pr * 4 + 1][e] +
                     po[pr * 4 + 2][e] + po[pr * 4 + 3][e];
    memory[(size_t)row * kE + e] = sm + mem_bias[m * kE + e];
    output[(size_t)row * kE + e] = so;
}

// -------------------------------------------------------------------------
// Fence-free 4-block spin barrier (R4-proven). Co-residency: 64 blocks on
// 256 CUs under a REGULAR launch — all workgroups dispatch immediately.
// Cross-block data uses agent-scope RELAXED atomics (no cache-maintenance).
// -------------------------------------------------------------------------
__device__ __forceinline__ void group_barrier(unsigned* ctr, unsigned target)
{
    __syncthreads();
    if (threadIdx.x == 0) {
        __hip_atomic_fetch_add(ctr, 1u, __ATOMIC_RELEASE, __HIP_MEMORY_SCOPE_AGENT);
        while (__hip_atomic_load(ctr, __ATOMIC_RELAXED, __HIP_MEMORY_SCOPE_AGENT) < target)
            __builtin_amdgcn_s_sleep(2);
    }
    __syncthreads();
}
__device__ __forceinline__ void cstore(float* p, float v) {
    __hip_atomic_store(p, v, __ATOMIC_RELAXED, __HIP_MEMORY_SCOPE_AGENT);
}
__device__ __forceinline__ float cload(const float* p) {
    return __hip_atomic_load(p, __ATOMIC_RELAXED, __HIP_MEMORY_SCOPE_AGENT);
}

// -------------------------------------------------------------------------
// Kernel 2 (REGULAR launch, 64 blocks x 1024 threads): q-embed + 3 hops.
// Block (b = bid>>2, qtr = bid&3) stages its quarter of memory[b]/output[b]
// into LDS once. Per hop, ONE barrier:
//   local scores -> exp (no max-sub: |s|=O(1), validated R4/R5)
//   publish numer[e]/denom partials -> barrier -> redundant combine + W mm.
// Partials double-buffered by hop parity. qtr==0 publishes relu(q) to xg.
// -------------------------------------------------------------------------
__global__ __launch_bounds__(1024) void hops_kernel(
    const int*   __restrict__ queries,   // [B,S]
    const float* __restrict__ q_bias,    // [VN,E]
    const float* __restrict__ memory,    // [B,M,E]
    const float* __restrict__ output,    // [B,M,E]
    const float* __restrict__ w_int,     // [E,E]
    const float* __restrict__ w_out,     // [E,E]
    float*       __restrict__ numer,     // [2,B,4,E]
    float*       __restrict__ denom,     // [2,B,4]
    float*       __restrict__ xg,        // [E,B] transposed
    unsigned*    __restrict__ bar)       // [B] counters (zeroed by embed)
{
    __shared__ __align__(16) float mem_lds[128 * kMS];  // 67584 B
    __shared__ __align__(16) float out_lds[128 * kE];   // 65536 B
    __shared__ float sc_q[128];
    __shared__ __align__(16) float q_s[kE];
    __shared__ float xb[kE];
    __shared__ __align__(16) float part8[8][kE];
    __shared__ int qidx[kS];

    const int bid = blockIdx.x;
    const int b   = bid >> 2;
    const int qtr = bid & 3;
    const int t   = threadIdx.x;
    unsigned* ctr = bar + b;

    // ---- stage quarter into LDS (coalesced float4) ----
    const float* memb = memory + ((size_t)b * kM + qtr * 128) * kE;
    const float* outb = output + ((size_t)b * kM + qtr * 128) * kE;
    #pragma unroll
    for (int i = 0; i < 4; ++i) {
        const int flat = t + i * 1024;
        const int rr = flat >> 5, ff = (flat & 31) * 4;
        *(float4*)&mem_lds[rr * kMS + ff] = *(const float4*)&memb[(size_t)rr * kE + ff];
        *(float4*)&out_lds[rr * kE  + ff] = *(const float4*)&outb[(size_t)rr * kE + ff];
    }
    if (t < kS) qidx[t] = queries[b * kS + t];
    __syncthreads();

    // ---- q embedding (threads 0..255) ----
    if (t < 256) {
        const int g = t >> 5, lane = t & 31, e0 = lane * 4;
        const float f0 = (float)(e0 - 63) * (1.0f / 1024.0f);
        const float f1 = (float)(e0 - 62) * (1.0f / 1024.0f);
        const float f2 = (float)(e0 - 61) * (1.0f / 1024.0f);
        const float f3 = (float)(e0 - 60) * (1.0f / 1024.0f);
        float4 a = {0.f, 0.f, 0.f, 0.f};
        #pragma unroll
        for (int j = 0; j < 4; ++j) {
            const int s   = g * 4 + j;
            const int idx = qidx[s];
            const int ci  = idx < kVN ? idx : (kVN - 1);
            const float live = (idx < kVN) ? 1.0f : 0.0f;
            const float sf = (float)(s - 15);
            const float4 v = *(const float4*)&q_bias[(size_t)ci * kE + e0];
            a.x = fmaf(v.x, fmaf(f0, sf, 1.f) * live, a.x);
            a.y = fmaf(v.y, fmaf(f1, sf, 1.f) * live, a.y);
            a.z = fmaf(v.z, fmaf(f2, sf, 1.f) * live, a.z);
            a.w = fmaf(v.w, fmaf(f3, sf, 1.f) * live, a.w);
        }
        *(float4*)&part8[g][e0] = a;
    }
    __syncthreads();
    if (t < kE) {
        float s = 0.f;
        #pragma unroll
        for (int g = 0; g < 8; ++g) s += part8[g][t];
        q_s[t] = s;
    }
    __syncthreads();

    const int grp = t >> 7;     // 0..7
    const int e   = t & 127;

    for (int hop = 0; hop < 3; ++hop) {
        // ---- scores for own 128 rows: 8 lanes x 16 e per row ----
        {
            const int rw = t >> 3, sub = t & 7;
            const float4* qv = (const float4*)&q_s[sub * 16];
            const float4* mv = (const float4*)&mem_lds[rw * kMS + sub * 16];
            float d = 0.f;
            #pragma unroll
            for (int i = 0; i < 4; ++i) {
                const float4 m4 = mv[i], q4 = qv[i];
                d = fmaf(m4.x, q4.x, d); d = fmaf(m4.y, q4.y, d);
                d = fmaf(m4.z, q4.z, d); d = fmaf(m4.w, q4.w, d);
            }
            d += __shfl_down(d, 4);
            d += __shfl_down(d, 2);
            d += __shfl_down(d, 1);
            if (sub == 0) sc_q[rw] = __expf(d);   // no max-sub: |s| = O(1)
        }
        __syncthreads();

        // ---- numer partial: numer[e] = sum_{m in qtr} e_m * out[m][e] ----
        {
            float acc = 0.f;
            const float* pp = &sc_q[grp * 16];
            const float* ob = &out_lds[grp * 16 * kE + e];
            #pragma unroll
            for (int j = 0; j < 16; ++j)
                acc = fmaf(pp[j], ob[j * kE], acc);
            part8[grp][e] = acc;
        }
        __syncthreads();

        const int pb = hop & 1;
        float* nq = numer + (((size_t)pb * kB + b) * 4 + qtr) * kE;
        if (t < kE) {
            float s = 0.f;
            #pragma unroll
            for (int g = 0; g < 8; ++g) s += part8[g][t];
            cstore(&nq[t], s);
        } else if (t < 192) {
            const int l = t - 128;
            float s2 = sc_q[l] + sc_q[l + 64];
            #pragma unroll
            for (int off = 32; off; off >>= 1) s2 += __shfl_down(s2, off);
            if (l == 0) cstore(&denom[((size_t)pb * kB + b) * 4 + qtr], s2);
        }

        group_barrier(ctr, 4u * (hop + 1));

        // ---- combine redundantly: xb = q + sum(numer)/sum(denom) ----
        if (t < kE) {
            const float* nn = numer + ((size_t)pb * kB + b) * 4 * kE;
            const float* dd = denom + ((size_t)pb * kB + b) * 4;
            const float ns = cload(&nn[t]) + cload(&nn[kE + t]) +
                             cload(&nn[2 * kE + t]) + cload(&nn[3 * kE + t]);
            const float ds = cload(&dd[0]) + cload(&dd[1]) +
                             cload(&dd[2]) + cload(&dd[3]);
            xb[t] = q_s[t] + ns / ds;
        }
        __syncthreads();

        // ---- q' = xb @ W (redundant, 8 k-groups of 16) ----
        {
            const float* w = (hop == 2) ? w_out : w_int;
            float acc = 0.f;
            #pragma unroll
            for (int j = 0; j < 16; ++j) {
                const int k = grp * 16 + j;
                acc = fmaf(xb[k], w[k * kE + e], acc);
            }
            part8[grp][e] = acc;
        }
        __syncthreads();
        if (t < kE) {
            float s = 0.f;
            #pragma unroll
            for (int g = 0; g < 8; ++g) s += part8[g][t];
            q_s[t] = s;
        }
        __syncthreads();
    }

    if (qtr == 0 && t < kE) xg[t * kB + b] = fmaxf(q_s[t], 0.f);
}

// -------------------------------------------------------------------------
// Kernel 3: out[b,v] = sum_e relu_x[b,e] * w_final[e,v].
// 250 blocks x 256 threads: v = bid*128 + (t&127), e-half = t>>7.
// xg read transposed -> uniform scalar loads; halves combined via LDS.
// -------------------------------------------------------------------------
__global__ __launch_bounds__(256) void final_kernel(
    const float* __restrict__ xg,   // [E,B]
    const float* __restrict__ wf,   // [E,V]
    float*       __restrict__ out)  // [B,V]
{
    __shared__ float ps[128 * kB];
    const int t = threadIdx.x;
    const int v = blockIdx.x * 128 + (t & 127);
    const int h = t >> 7;

    float acc[kB];
    #pragma unroll
    for (int b = 0; b < kB; ++b) acc[b] = 0.f;

    const int e0 = h * 64;
    #pragma unroll 4
    for (int ei = 0; ei < 64; ++ei) {
        const int e = e0 + ei;
        const float wv = wf[(size_t)e * kV + v];
        const float* xr = xg + e * kB;
        #pragma unroll
        for (int b = 0; b < kB; ++b) acc[b] = fmaf(xr[b], wv, acc[b]);
    }
    if (h == 1) {
        #pragma unroll
        for (int b = 0; b < kB; ++b) ps[(t & 127) * kB + b] = acc[b];
    }
    __syncthreads();
    if (h == 0) {
        #pragma unroll
        for (int b = 0; b < kB; ++b)
            out[(size_t)b * kV + v] = acc[b] + ps[(t & 127) * kB + b];
    }
}

// -------------------------------------------------------------------------
extern "C" void kernel_launch(void* const* d_in, const int* in_sizes, int n_in,
                              void* d_out, int out_size, void* d_ws, size_t ws_size,
                              hipStream_t stream)
{
    const int*   queries  = (const int*)  d_in[0];
    const int*   stories  = (const int*)  d_in[1];
    const float* q_bias   = (const float*)d_in[2];
    const float* st_bias  = (const float*)d_in[3];
    const float* mem_bias = (const float*)d_in[4];
    const float* out_bias = (const float*)d_in[5];
    const float* w_int    = (const float*)d_in[6];
    const float* w_out    = (const float*)d_in[7];
    const float* w_final  = (const float*)d_in[8];
    float* out = (float*)d_out;

    // ws layout (floats): memory | output | numer | denom | xg | bar
    float* memory = (float*)d_ws;
    float* output = memory + (size_t)kB * kM * kE;        // 1,048,576
    float* numer  = output + (size_t)kB * kM * kE;        // 1,048,576
    float* denom  = numer  + 2 * kB * 4 * kE;             // 16,384
    float* xg     = denom  + 2 * kB * 4;                  // 128
    unsigned* bar = (unsigned*)(xg + kE * kB);            // 2,048

    embed_stories_kernel<<<dim3((kB * kM) / 2), dim3(256), 0, stream>>>(
        stories, st_bias, out_bias, mem_bias, memory, output, bar);

    hops_kernel<<<dim3(64), dim3(1024), 0, stream>>>(
        queries, q_bias, memory, output, w_int, w_out,
        numer, denom, xg, bar);

    final_kernel<<<dim3(kV / 128), dim3(256), 0, stream>>>(xg, w_final, out);
}